// Round 12
// baseline (77.083 us; speedup 1.0000x reference)
//
#include <hip/hip_runtime.h>
#include <math.h>

#define NCLS   100
#define ITERS  100
#define RPBR   8             // REAL batch rows per block (rows 8-15 duplicate 0-7)
#define RPB    16            // MFMA M
#define XS     136           // LDS x row stride, bf16 elems
#define XBUF   (RPB * XS)

typedef short  bf16x8 __attribute__((ext_vector_type(8)));   // 8 bf16 in 4 VGPRs
typedef float  f32x4  __attribute__((ext_vector_type(4)));

#if __has_builtin(__builtin_amdgcn_rcpf)
__device__ __forceinline__ float fast_rcp(float x) { return __builtin_amdgcn_rcpf(x); }
#else
__device__ __forceinline__ float fast_rcp(float x) { return 1.0f / x; }
#endif

#if __has_builtin(__builtin_amdgcn_exp2f)
__device__ __forceinline__ float fast_exp2(float x) { return __builtin_amdgcn_exp2f(x); }
#else
__device__ __forceinline__ float fast_exp2(float x) { return exp2f(x); }
#endif

__device__ __forceinline__ unsigned bf16_rne(float f) {   // f32 -> bf16 bits, RNE
    unsigned u = __float_as_uint(f);
    return (u + 0x7FFFu + ((u >> 16) & 1u)) >> 16;
}
__device__ __forceinline__ float wave_sum(float v) {
#pragma unroll
    for (int m = 32; m > 0; m >>= 1) v += __shfl_xor(v, m, 64);
    return v;
}
__device__ __forceinline__ bool any_ne(f32x4 a, f32x4 b) {
    return (a[0] != b[0]) | (a[1] != b[1]) | (a[2] != b[2]) | (a[3] != b[3]);
}

#define MFMA_B(Af, Bf, Cf) __builtin_amdgcn_mfma_f32_16x16x32_bf16(Af, Bf, Cf, 0, 0, 0)

extern "C" __global__ void sk_zero_out(float* out) { out[0] = 0.0f; }

// One Sinkhorn half-iteration: X = MG ⊘ (K x_src); writes bf16 X to DST,
// exports fp32 X into X0V/X1V and the raw MFMA accs into accP0_/accP1_.
#define HALF(SRC, DST, MG0, MG1, X0V, X1V)                                   \
    {                                                                        \
        bf16x8 A_[4];                                                        \
        _Pragma("unroll")                                                    \
        for (int s_ = 0; s_ < 4; ++s_)                                       \
            A_[s_] = *(const bf16x8*)((SRC) + lc * XS + s_ * 32 + quad * 8); \
        f32x4 aA_ = {0,0,0,0}, aB_ = {0,0,0,0};                              \
        f32x4 bA_ = {0,0,0,0}, bB_ = {0,0,0,0};                              \
        aA_ = MFMA_B(A_[0], B0[0], aA_);  bA_ = MFMA_B(A_[0], B1[0], bA_);   \
        aB_ = MFMA_B(A_[2], B0[2], aB_);  bB_ = MFMA_B(A_[2], B1[2], bB_);   \
        aA_ = MFMA_B(A_[1], B0[1], aA_);  bA_ = MFMA_B(A_[1], B1[1], bA_);   \
        aB_ = MFMA_B(A_[3], B0[3], aB_);  bB_ = MFMA_B(A_[3], B1[3], bB_);   \
        f32x4 acc0_ = aA_ + aB_;                                             \
        f32x4 acc1_ = bA_ + bB_;                                             \
        _Pragma("unroll")                                                    \
        for (int r_ = 0; r_ < 4; ++r_) {                                     \
            int m_ = quad * 4 + r_;                                          \
            X0V[r_] = MG0[r_] * fast_rcp(acc0_[r_] + bias0);                 \
            X1V[r_] = MG1[r_] * fast_rcp(acc1_[r_] + bias1);                 \
            (DST)[m_ * XS + t0n] = (short)bf16_rne(X0V[r_]);                 \
            (DST)[m_ * XS + t1n] = (short)bf16_rne(X1V[r_]);                 \
        }                                                                    \
        accP0_ = acc0_; accP1_ = acc1_;                                      \
    }

// ---------------------------------------------------------------------------
// Fully fused Sinkhorn (round-11 structure) with 8 REAL rows per block
// (rows 8-15 are exact duplicates of 0-7 -> bit-identical lanes; final sum
// is halved). Grid = rows/8 = 512 -> 2 independent barrier domains per CU,
// whose barrier stalls mutually hide (MFMA/VALU co-scheduling, m114).
// Warm start b0 = nu; early exit on bf16 stationarity of a full pair.
// ---------------------------------------------------------------------------
extern "C" __global__ void __launch_bounds__(256)
sk_fused(const float* __restrict__ pred, const int* __restrict__ target,
         float* __restrict__ out, int rows)
{
    __shared__ short xs[2 * XBUF];
    __shared__ __align__(16) float aux[RPB * 104];  // muL pre-loop; SsumP/zP/sclS post
    __shared__ int flagS[4];                        // per-wave change flags (1/pair)

    const int tid  = threadIdx.x;
    const int lane = tid & 63;
    const int wave = tid >> 6;        // 0..3
    const int quad = lane >> 4;       // 0..3
    const int lc   = lane & 15;
    const int row0 = blockIdx.x * RPBR;

    // ---- mu = normalize(softmax(pred_row) + STAB): 16 threads per row ----
    // rows 8-15 duplicate rows 0-7 (same pred row -> identical aux content)
    {
        const int r = tid >> 4;       // 0..15
        const int c = tid & 15;
        const float* p = pred + (size_t)(row0 + (r & 7)) * NCLS;
        const float l2e = 1.44269504089f;
        float v[7];
        float mx = -3.4e38f;
#pragma unroll
        for (int q = 0; q < 7; ++q) {
            int j = c + q * 16;
            v[q] = (j < NCLS) ? p[j] : -3.4e38f;
            mx = fmaxf(mx, v[q]);
        }
#pragma unroll
        for (int m = 8; m >= 1; m >>= 1) mx = fmaxf(mx, __shfl_xor(mx, m, 64));
        float s = 0.f;
#pragma unroll
        for (int q = 0; q < 7; ++q) {
            v[q] = (c + q * 16 < NCLS) ? fast_exp2((v[q] - mx) * l2e) : 0.f;
            s += v[q];
        }
#pragma unroll
        for (int m = 8; m >= 1; m >>= 1) s += __shfl_xor(s, m, 64);
        float invS = 1.f / s;
        float s2 = 0.f;
#pragma unroll
        for (int q = 0; q < 7; ++q) {
            if (c + q * 16 < NCLS) { v[q] = v[q] * invS + 1e-6f; s2 += v[q]; }
        }
#pragma unroll
        for (int m = 8; m >= 1; m >>= 1) s2 += __shfl_xor(s2, m, 64);
        float invM = 1.f / s2;
#pragma unroll
        for (int q = 0; q < 7; ++q) {
            int j = c + q * 16;
            if (j < NCLS) aux[r * 104 + j] = v[q] * invM;
        }
    }

    // ---- this wave's N-columns ----
    const int t0n = (2 * wave) * 16 + lc;
    const int t1n = (2 * wave + 1) * 16 + lc;
    const float bias0 = (t0n >= NCLS) ? 1.0f : 0.0f;   // keep rcp input > 0 on pad cols
    const float bias1 = (t1n >= NCLS) ? 1.0f : 0.0f;

    // ---- static B-fragments: B[k=quad*8+j][n] = w(k-n), bf16, Toeplitz ----
    const float c2 = -14.4269504089f / 9801.0f;        // -10*log2(e)/9801
    bf16x8 B0[4], B1[4];
#pragma unroll
    for (int s = 0; s < 4; ++s) {
#pragma unroll
        for (int j = 0; j < 8; ++j) {
            int k  = s * 32 + quad * 8 + j;
            int d0 = k - t0n;
            int d1 = k - t1n;
            B0[s][j] = (short)bf16_rne(fast_exp2(c2 * (float)(d0 * d0)));
            B1[s][j] = (short)bf16_rne(fast_exp2(c2 * (float)(d1 * d1)));
        }
    }

    __syncthreads();   // muL ready

    // ---- marginal fragments in C-layout (row m = quad*4+r, col n) ----
    f32x4 mu0f, mu1f, nu0f, nu1f;
    const float invN = 1.0f / (1.0f + (float)NCLS * 1e-6f);
#pragma unroll
    for (int r = 0; r < 4; ++r) {
        int m = quad * 4 + r;
        mu0f[r] = (t0n < NCLS) ? aux[m * 104 + t0n] : 0.f;
        mu1f[r] = (t1n < NCLS) ? aux[m * 104 + t1n] : 0.f;
        int tg = (int)target[row0 + (m & 7)];          // duplicate rows 8-15
        nu0f[r] = (t0n < NCLS) ? ((((t0n == tg) ? 1.f : 0.f) + 1e-6f) * invN) : 0.f;
        nu1f[r] = (t1n < NCLS) ? ((((t1n == tg) ? 1.f : 0.f) + 1e-6f) * invN) : 0.f;
    }

    // ---- WARM START: x = b0 = nu (pad cols 0); buffer 0 ----
#pragma unroll
    for (int r = 0; r < 4; ++r) {
        int m = quad * 4 + r;
        xs[m * XS + t0n] = (short)bf16_rne(nu0f[r]);
        xs[m * XS + t1n] = (short)bf16_rne(nu1f[r]);
    }
    __syncthreads();

    // ---- main pair loop with stationarity early-exit (<= 99 pairs) ----
    f32x4 pvE0 = {-1.f,-1.f,-1.f,-1.f}, pvE1 = pvE0, pvO0 = pvE0, pvO1 = pvE0;
    f32x4 xT0, xT1, accP0_, accP1_;
    for (int pair = 0; pair < ITERS - 1; ++pair) {
        // even half: a = mu/(K b), buf0 -> buf1
        HALF(xs, xs + XBUF, mu0f, mu1f, xT0, xT1);
        bool chgE = any_ne(accP0_, pvE0) || any_ne(accP1_, pvE1);
        pvE0 = accP0_; pvE1 = accP1_;
        __syncthreads();
        // odd half: b = nu/(K a), buf1 -> buf0
        HALF(xs + XBUF, xs, nu0f, nu1f, xT0, xT1);
        bool chgO = any_ne(accP0_, pvO0) || any_ne(accP1_, pvO1);
        pvO0 = accP0_; pvO1 = accP1_;
        int anyv = __any((int)(chgE || chgO));
        if (lane == 0) flagS[wave] = anyv;
        __syncthreads();
        if ((flagS[0] | flagS[1] | flagS[2] | flagS[3]) == 0) break;
    }

    // ---- capture pair: final a (fp32) and b (fp32); b bf16 lands in buf0 ----
    f32x4 aR0, aR1, bR0, bR1;
    HALF(xs, xs + XBUF, mu0f, mu1f, aR0, aR1);
    __syncthreads();
    HALF(xs + XBUF, xs, nu0f, nu1f, bR0, bR1);
    __syncthreads();

    // ================= fused epilogue (round-10-verified math) =================
    // t = K b  (A from buffer 0)
    f32x4 t0a = {0.f, 0.f, 0.f, 0.f};
    f32x4 t1a = {0.f, 0.f, 0.f, 0.f};
    {
        bf16x8 A[4];
#pragma unroll
        for (int s = 0; s < 4; ++s)
            A[s] = *(const bf16x8*)(xs + lc * XS + s * 32 + quad * 8);
#pragma unroll
        for (int s = 0; s < 4; ++s) {
            t0a = MFMA_B(A[s], B0[s], t0a);
            t1a = MFMA_B(A[s], B1[s], t1a);
        }
    }

    // scl = mu / (a*t + n*STAB);  a' = a*scl.  Write a' (buf1) and scl bf16.
    float* SsumP = aux;                     // [4 waves][16 m] floats (256 B)
    float* zP    = aux + 64;                // [4] block-reduce slots
    short* sclS  = (short*)(aux + 128);     // [RPB][XS] bf16 (4352 B)
    short* apS   = xs + XBUF;               // buffer 1, a dead

#pragma unroll
    for (int r = 0; r < 4; ++r) {
        int m = quad * 4 + r;
        float scl0 = mu0f[r] * fast_rcp(fmaf(aR0[r], t0a[r], (float)NCLS * 1e-6f));
        float scl1 = mu1f[r] * fast_rcp(fmaf(aR1[r], t1a[r], (float)NCLS * 1e-6f));
        apS[m * XS + t0n]  = (short)bf16_rne(aR0[r] * scl0);
        apS[m * XS + t1n]  = (short)bf16_rne(aR1[r] * scl1);
        sclS[m * XS + t0n] = (short)bf16_rne(scl0);
        sclS[m * XS + t1n] = (short)bf16_rne(scl1);
        // partial Ssum over this wave's 32 cols (16-lane quad reduce)
        float ps = scl0 + scl1;
#pragma unroll
        for (int w = 8; w >= 1; w >>= 1) ps += __shfl_xor(ps, w, 64);
        if (lc == 0) SsumP[wave * 16 + m] = ps;
    }
    __syncthreads();

    // Ssum[m] = sum over 4 waves
    f32x4 Ssum;
#pragma unroll
    for (int r = 0; r < 4; ++r) {
        int m = quad * 4 + r;
        Ssum[r] = SsumP[m] + SsumP[16 + m] + SsumP[32 + m] + SsumP[48 + m];
    }

    // B-frags for K.C and C (Toeplitz): KC(d) = K(d)*d^2/9801, C(d) = d^2/9801
    bf16x8 KC0[4], KC1[4], C0[4], C1[4];
    const float cinv = 1.0f / 9801.0f;
#pragma unroll
    for (int s = 0; s < 4; ++s) {
#pragma unroll
        for (int j = 0; j < 8; ++j) {
            int k  = s * 32 + quad * 8 + j;
            int d0 = k - t0n;
            int d1 = k - t1n;
            float c0 = (float)(d0 * d0) * cinv;
            float c1 = (float)(d1 * d1) * cinv;
            KC0[s][j] = (short)bf16_rne(fast_exp2(c2 * (float)(d0 * d0)) * c0);
            KC1[s][j] = (short)bf16_rne(fast_exp2(c2 * (float)(d1 * d1)) * c1);
            C0[s][j]  = (short)bf16_rne(c0);
            C1[s][j]  = (short)bf16_rne(c1);
        }
    }

    // q = K a',  mm = (K.C) a',  cs = C scl   (A-frags from apS / sclS)
    f32x4 q0 = {0,0,0,0}, q1 = {0,0,0,0};
    f32x4 m0 = {0,0,0,0}, m1 = {0,0,0,0};
    f32x4 s0 = {0,0,0,0}, s1 = {0,0,0,0};
    {
        bf16x8 Aa[4], As[4];
#pragma unroll
        for (int s = 0; s < 4; ++s) {
            Aa[s] = *(const bf16x8*)(apS  + lc * XS + s * 32 + quad * 8);
            As[s] = *(const bf16x8*)(sclS + lc * XS + s * 32 + quad * 8);
        }
#pragma unroll
        for (int s = 0; s < 4; ++s) {
            q0 = MFMA_B(Aa[s], B0[s],  q0);
            q1 = MFMA_B(Aa[s], B1[s],  q1);
            m0 = MFMA_B(Aa[s], KC0[s], m0);
            m1 = MFMA_B(Aa[s], KC1[s], m1);
            s0 = MFMA_B(As[s], C0[s],  s0);
            s1 = MFMA_B(As[s], C1[s],  s1);
        }
    }

    // cost: z = sum_j nu_j/(b_j q_j + STAB*Ssum) * (b_j mm_j + STAB*cs_j)
    // rows 8-15 are bit-identical duplicates of 0-7 -> halve the total.
    float z = 0.f;
#pragma unroll
    for (int r = 0; r < 4; ++r) {
        float col0 = fmaf(bR0[r], q0[r], 1e-6f * Ssum[r]);
        float col1 = fmaf(bR1[r], q1[r], 1e-6f * Ssum[r]);
        float in0  = fmaf(bR0[r], m0[r], 1e-6f * s0[r]);
        float in1  = fmaf(bR1[r], m1[r], 1e-6f * s1[r]);
        z += nu0f[r] * fast_rcp(col0) * in0 + nu1f[r] * fast_rcp(col1) * in1;
    }
    z = wave_sum(z);
    if (lane == 0) zP[wave] = z;
    __syncthreads();
    if (tid == 0) {
        float tot = zP[0] + zP[1] + zP[2] + zP[3];
        atomicAdd(out, 0.5f * tot / (float)rows);
    }
}

extern "C" void kernel_launch(void* const* d_in, const int* in_sizes, int n_in,
                              void* d_out, int out_size, void* d_ws, size_t ws_size,
                              hipStream_t stream)
{
    const float* pred   = (const float*)d_in[0];
    const int*   target = (const int*)d_in[1];
    float*       out    = (float*)d_out;
    const int    rows   = in_sizes[0] / NCLS;   // 4096

    hipLaunchKernelGGL(sk_zero_out, dim3(1), dim3(1), 0, stream, out);
    hipLaunchKernelGGL(sk_fused, dim3(rows / RPBR), dim3(256), 0, stream,
                       pred, target, out, rows);
}

// Round 13
// 72.004 us; speedup vs baseline: 1.0705x; 1.0705x over previous
//
#include <hip/hip_runtime.h>
#include <math.h>

#define NCLS   100
#define ITERS  100
#define RPW    16            // batch rows per wave (MFMA N)
#define XS     136           // LDS x row stride, shorts
#define XBUF   (RPW * XS)
#define AUXS   112           // mu row stride, floats

typedef short  bf16x8 __attribute__((ext_vector_type(8)));   // 8 bf16 in 4 VGPRs
typedef float  f32x4  __attribute__((ext_vector_type(4)));

#if __has_builtin(__builtin_amdgcn_rcpf)
__device__ __forceinline__ float fast_rcp(float x) { return __builtin_amdgcn_rcpf(x); }
#else
__device__ __forceinline__ float fast_rcp(float x) { return 1.0f / x; }
#endif

#if __has_builtin(__builtin_amdgcn_exp2f)
__device__ __forceinline__ float fast_exp2(float x) { return __builtin_amdgcn_exp2f(x); }
#else
__device__ __forceinline__ float fast_exp2(float x) { return exp2f(x); }
#endif

__device__ __forceinline__ unsigned bf16_rne(float f) {   // f32 -> bf16 bits, RNE
    unsigned u = __float_as_uint(f);
    return (u + 0x7FFFu + ((u >> 16) & 1u)) >> 16;
}
__device__ __forceinline__ float wave_sum(float v) {
#pragma unroll
    for (int m = 32; m > 0; m >>= 1) v += __shfl_xor(v, m, 64);
    return v;
}

#define MFMA_B(Af, Bf, Cf) __builtin_amdgcn_mfma_f32_16x16x32_bf16(Af, Bf, Cf, 0, 0, 0)

extern "C" __global__ void sk_zero_out(float* out) { out[0] = 0.0f; }

// K-apply in transposed form: OUT[t][r] = (FR . x)[class = 16t+quad*4+r][batch = lc]
// A = FR (static Toeplitz frags, index u = t-2s+6), B = x from LDS.
// A layout: A[m=lc][k=quad*8+j];  B layout: B[k=quad*8+j][n=lc];
// C layout: col(lc)=batch, row(quad*4+r)=class-within-tile.  (All three roles
// verified in-session by the round-8..11 kernels.)
#define MATV(BUFP, FR, OUT)                                                   \
    {                                                                         \
        bf16x8 Bv_[4];                                                        \
        _Pragma("unroll")                                                     \
        for (int s_ = 0; s_ < 4; ++s_)                                        \
            Bv_[s_] = *(const bf16x8*)((BUFP) + lc * XS + 32 * s_ + quad * 8);\
        _Pragma("unroll")                                                     \
        for (int t_ = 0; t_ < 7; ++t_) OUT[t_] = (f32x4){0.f, 0.f, 0.f, 0.f}; \
        _Pragma("unroll")                                                     \
        for (int s_ = 0; s_ < 4; ++s_)                                        \
            _Pragma("unroll")                                                 \
            for (int t_ = 0; t_ < 7; ++t_)                                    \
                OUT[t_] = MFMA_B(FR[t_ - 2 * s_ + 6], Bv_[s_], OUT[t_]);      \
    }

// One half-iteration: x_new = MG ⊘ (K x), wave-private, no barriers.
// XV receives the fp32 x_new (capture); AC keeps the raw accs (stationarity).
#define HALFI(MG, XV, AC)                                                     \
    {                                                                         \
        MATV(xs, KF, AC)                                                      \
        _Pragma("unroll")                                                     \
        for (int t_ = 0; t_ < 7; ++t_) {                                      \
            _Pragma("unroll")                                                 \
            for (int r_ = 0; r_ < 4; ++r_) {                                  \
                float den = AC[t_][r_] + ((t_ == 6) ? b6 : 0.0f);             \
                XV[t_][r_] = MG[t_][r_] * fast_rcp(den);                      \
            }                                                                 \
            unsigned u0_ = bf16_rne(XV[t_][0]) | (bf16_rne(XV[t_][1]) << 16); \
            unsigned u1_ = bf16_rne(XV[t_][2]) | (bf16_rne(XV[t_][3]) << 16); \
            *(uint2*)(xs + lc * XS + 16 * t_ + quad * 4) = make_uint2(u0_, u1_); \
        }                                                                     \
    }

// ---------------------------------------------------------------------------
// Barrier-free fused Sinkhorn: 1 wave owns 16 batch rows end-to-end.
// K (Toeplitz) as MFMA A-operand: frag(t,s) = frag(t-2s) -> 13 frags, 52 VGPR.
// x state [16 batch][128 class] bf16 in wave-private LDS; same-wave DS ops are
// in-order, so NO __syncthreads anywhere. Warm start b0 = nu; early exit when
// the odd-half accs are bf16-bit-stationary (b repeats -> all future repeats).
// ---------------------------------------------------------------------------
extern "C" __global__ void __launch_bounds__(64)
sk_fused(const float* __restrict__ pred, const int* __restrict__ target,
         float* __restrict__ out, int rows)
{
    __shared__ short xs[3 * XBUF];          // x | a' | scl
    __shared__ float aux[RPW * AUXS];       // mu, f32

    const int lane = threadIdx.x & 63;
    const int quad = lane >> 4;
    const int lc   = lane & 15;
    const int row0 = blockIdx.x * RPW;

    // ---- mu = normalize(softmax(pred_row) + STAB): 4 lanes per row (quads) ----
    {
        const float* p = pred + (size_t)(row0 + lc) * NCLS;
        const float l2e = 1.44269504089f;
        float v[25];
        float mx = -3.4e38f;
#pragma unroll
        for (int k = 0; k < 25; ++k) { v[k] = p[quad + 4 * k]; mx = fmaxf(mx, v[k]); }
        mx = fmaxf(mx, __shfl_xor(mx, 16, 64));
        mx = fmaxf(mx, __shfl_xor(mx, 32, 64));
        float s = 0.f;
#pragma unroll
        for (int k = 0; k < 25; ++k) { v[k] = fast_exp2((v[k] - mx) * l2e); s += v[k]; }
        s += __shfl_xor(s, 16, 64);
        s += __shfl_xor(s, 32, 64);
        float invS = 1.f / s, s2 = 0.f;
#pragma unroll
        for (int k = 0; k < 25; ++k) { v[k] = v[k] * invS + 1e-6f; s2 += v[k]; }
        s2 += __shfl_xor(s2, 16, 64);
        s2 += __shfl_xor(s2, 32, 64);
        float invM = 1.f / s2;
#pragma unroll
        for (int k = 0; k < 25; ++k) aux[lc * AUXS + quad + 4 * k] = v[k] * invM;
    }

    // ---- static K A-frags (Toeplitz): KF[u][j] = w(16(u-6) + lc - quad*8 - j) ----
    const float c2 = -14.4269504089f / 9801.0f;   // -10*log2(e)/9801
    bf16x8 KF[13];
#pragma unroll
    for (int u = 0; u < 13; ++u)
#pragma unroll
        for (int j = 0; j < 8; ++j) {
            int d = 16 * (u - 6) + lc - quad * 8 - j;
            KF[u][j] = (short)bf16_rne(fast_exp2(c2 * (float)(d * d)));
        }

    // ---- per-lane marginals: class = 16t+quad*4+r, batch = lc ----
    // (aux writes above are same-wave DS ops -> in-order, reads below are safe)
    f32x4 muT[7], nuT[7];
    const float invN = 1.0f / (1.0f + (float)NCLS * 1e-6f);
#pragma unroll
    for (int t = 0; t < 7; ++t)
        muT[t] = *(const f32x4*)(aux + lc * AUXS + 16 * t + quad * 4);
    if (quad != 0) muT[6] = (f32x4){0.f, 0.f, 0.f, 0.f};   // pad classes 100..111
    const int tgt = target[row0 + lc];
#pragma unroll
    for (int t = 0; t < 7; ++t)
#pragma unroll
        for (int r = 0; r < 4; ++r) {
            int c = 16 * t + quad * 4 + r;
            nuT[t][r] = (c < NCLS) ? ((((c == tgt) ? 1.f : 0.f) + 1e-6f) * invN) : 0.f;
        }
    const float b6 = (quad != 0) ? 1.0f : 0.0f;   // rcp bias on pad classes

    // ---- warm start: x = b0 = nu; pad tile 7 zeroed once (never rewritten) ----
#pragma unroll
    for (int t = 0; t < 7; ++t) {
        unsigned u0 = bf16_rne(nuT[t][0]) | (bf16_rne(nuT[t][1]) << 16);
        unsigned u1 = bf16_rne(nuT[t][2]) | (bf16_rne(nuT[t][3]) << 16);
        *(uint2*)(xs + lc * XS + 16 * t + quad * 4) = make_uint2(u0, u1);
    }
    *(uint2*)(xs + lc * XS + 112 + quad * 4) = make_uint2(0u, 0u);

    // ---- pair loop with odd-half stationarity early-exit (<= 99 pairs) ----
    f32x4 ac[7], xv[7], prevB[7];
#pragma unroll
    for (int t = 0; t < 7; ++t) prevB[t] = (f32x4){-1.f, -1.f, -1.f, -1.f};
    for (int pr = 0; pr < ITERS - 1; ++pr) {
        HALFI(muT, xv, ac)                      // a = mu/(K b)
        HALFI(nuT, xv, ac)                      // b = nu/(K a)
        bool chg = false;
#pragma unroll
        for (int t = 0; t < 7; ++t)
#pragma unroll
            for (int r = 0; r < 4; ++r) {
                chg = chg || (ac[t][r] != prevB[t][r]);
                prevB[t][r] = ac[t][r];
            }
        if (__any((int)chg) == 0) break;        // b bit-stationary -> done
    }

    // ---- capture pair: final a, b in fp32 (b bf16 lands in xs) ----
    f32x4 aR[7], bR[7];
    HALFI(muT, aR, ac)
    HALFI(nuT, bR, ac)

    // ================= fused epilogue (R11-verified algebra, transposed) ======
    // tv = K b
    f32x4 tv[7];
    MATV(xs, KF, tv)

    // scl = mu/(a*tv + n*STAB); a' = a*scl; Ssum per batch (cross-quad reduce)
    short* apS  = xs + XBUF;
    short* sclS = xs + 2 * XBUF;
    float Ssum = 0.f;
#pragma unroll
    for (int t = 0; t < 7; ++t) {
        float sv[4], av[4];
#pragma unroll
        for (int r = 0; r < 4; ++r) {
            float s = muT[t][r] * fast_rcp(fmaf(aR[t][r], tv[t][r], (float)NCLS * 1e-6f));
            sv[r] = s;
            av[r] = aR[t][r] * s;
            Ssum += s;
        }
        unsigned a0 = bf16_rne(av[0]) | (bf16_rne(av[1]) << 16);
        unsigned a1 = bf16_rne(av[2]) | (bf16_rne(av[3]) << 16);
        *(uint2*)(apS + lc * XS + 16 * t + quad * 4) = make_uint2(a0, a1);
        unsigned s0 = bf16_rne(sv[0]) | (bf16_rne(sv[1]) << 16);
        unsigned s1 = bf16_rne(sv[2]) | (bf16_rne(sv[3]) << 16);
        *(uint2*)(sclS + lc * XS + 16 * t + quad * 4) = make_uint2(s0, s1);
    }
    *(uint2*)(apS  + lc * XS + 112 + quad * 4) = make_uint2(0u, 0u);
    *(uint2*)(sclS + lc * XS + 112 + quad * 4) = make_uint2(0u, 0u);
    Ssum += __shfl_xor(Ssum, 16, 64);
    Ssum += __shfl_xor(Ssum, 32, 64);

    // q = K a'
    f32x4 qv[7];
    MATV(apS, KF, qv)

    // mm = (K.C) a'   (KC frags replace KF-liveness)
    const float cinv = 1.0f / 9801.0f;
    bf16x8 KC[13];
#pragma unroll
    for (int u = 0; u < 13; ++u)
#pragma unroll
        for (int j = 0; j < 8; ++j) {
            int d = 16 * (u - 6) + lc - quad * 8 - j;
            float cc = (float)(d * d) * cinv;
            KC[u][j] = (short)bf16_rne(fast_exp2(c2 * (float)(d * d)) * cc);
        }
    f32x4 mmv[7];
    MATV(apS, KC, mmv)

    // cs = C scl
    bf16x8 CF[13];
#pragma unroll
    for (int u = 0; u < 13; ++u)
#pragma unroll
        for (int j = 0; j < 8; ++j) {
            int d = 16 * (u - 6) + lc - quad * 8 - j;
            CF[u][j] = (short)bf16_rne((float)(d * d) * cinv);
        }
    f32x4 csv[7];
    MATV(sclS, CF, csv)

    // cost: z = sum nu/(b q + STAB*Ssum) * (b mm + STAB*cs); wave covers all
    // (class, batch) cells of its 16 rows -> wave_sum = sum of 16 row-costs.
    float z = 0.f;
#pragma unroll
    for (int t = 0; t < 7; ++t)
#pragma unroll
        for (int r = 0; r < 4; ++r) {
            float col = fmaf(bR[t][r], qv[t][r], 1e-6f * Ssum);
            float inn = fmaf(bR[t][r], mmv[t][r], 1e-6f * csv[t][r]);
            z += nuT[t][r] * fast_rcp(col) * inn;
        }
    z = wave_sum(z);
    if (lane == 0) atomicAdd(out, z / (float)rows);
}

extern "C" void kernel_launch(void* const* d_in, const int* in_sizes, int n_in,
                              void* d_out, int out_size, void* d_ws, size_t ws_size,
                              hipStream_t stream)
{
    const float* pred   = (const float*)d_in[0];
    const int*   target = (const int*)d_in[1];
    float*       out    = (float*)d_out;
    const int    rows   = in_sizes[0] / NCLS;   // 4096

    hipLaunchKernelGGL(sk_zero_out, dim3(1), dim3(1), 0, stream, out);
    hipLaunchKernelGGL(sk_fused, dim3(rows / RPW), dim3(64), 0, stream,
                       pred, target, out, rows);
}

// Round 14
// 67.236 us; speedup vs baseline: 1.1464x; 1.0709x over previous
//
#include <hip/hip_runtime.h>
#include <math.h>

#define NCLS   100
#define ITERS  100
#define RPB    16            // batch rows per block (MFMA M)
#define XS     136           // LDS x row stride, bf16 elems
#define XBUF   (RPB * XS)

typedef short  bf16x8 __attribute__((ext_vector_type(8)));   // 8 bf16 in 4 VGPRs
typedef float  f32x4  __attribute__((ext_vector_type(4)));

#if __has_builtin(__builtin_amdgcn_rcpf)
__device__ __forceinline__ float fast_rcp(float x) { return __builtin_amdgcn_rcpf(x); }
#else
__device__ __forceinline__ float fast_rcp(float x) { return 1.0f / x; }
#endif

#if __has_builtin(__builtin_amdgcn_exp2f)
__device__ __forceinline__ float fast_exp2(float x) { return __builtin_amdgcn_exp2f(x); }
#else
__device__ __forceinline__ float fast_exp2(float x) { return exp2f(x); }
#endif

__device__ __forceinline__ unsigned bf16_rne(float f) {   // f32 -> bf16 bits, RNE
    unsigned u = __float_as_uint(f);
    return (u + 0x7FFFu + ((u >> 16) & 1u)) >> 16;
}
__device__ __forceinline__ float wave_sum(float v) {
#pragma unroll
    for (int m = 32; m > 0; m >>= 1) v += __shfl_xor(v, m, 64);
    return v;
}
__device__ __forceinline__ bool any_ne(f32x4 a, f32x4 b) {
    return (a[0] != b[0]) | (a[1] != b[1]) | (a[2] != b[2]) | (a[3] != b[3]);
}

#define MFMA_B(Af, Bf, Cf) __builtin_amdgcn_mfma_f32_16x16x32_bf16(Af, Bf, Cf, 0, 0, 0)

extern "C" __global__ void sk_zero_out(float* out) { out[0] = 0.0f; }

// One Sinkhorn half-iteration: X = MG ⊘ (K x_src); writes bf16 X to DST,
// exports fp32 X into X0V/X1V and the raw MFMA accs into accP0_/accP1_.
// Four 2-deep MFMA chains (shorter dep chain than 2x4).
#define HALF(SRC, DST, MG0, MG1, X0V, X1V)                                   \
    {                                                                        \
        bf16x8 A_[4];                                                        \
        _Pragma("unroll")                                                    \
        for (int s_ = 0; s_ < 4; ++s_)                                       \
            A_[s_] = *(const bf16x8*)((SRC) + lc * XS + s_ * 32 + quad * 8); \
        f32x4 aA_ = {0,0,0,0}, aB_ = {0,0,0,0};                              \
        f32x4 bA_ = {0,0,0,0}, bB_ = {0,0,0,0};                              \
        aA_ = MFMA_B(A_[0], B0[0], aA_);  bA_ = MFMA_B(A_[0], B1[0], bA_);   \
        aB_ = MFMA_B(A_[2], B0[2], aB_);  bB_ = MFMA_B(A_[2], B1[2], bB_);   \
        aA_ = MFMA_B(A_[1], B0[1], aA_);  bA_ = MFMA_B(A_[1], B1[1], bA_);   \
        aB_ = MFMA_B(A_[3], B0[3], aB_);  bB_ = MFMA_B(A_[3], B1[3], bB_);   \
        f32x4 acc0_ = aA_ + aB_;                                             \
        f32x4 acc1_ = bA_ + bB_;                                             \
        _Pragma("unroll")                                                    \
        for (int r_ = 0; r_ < 4; ++r_) {                                     \
            int m_ = quad * 4 + r_;                                          \
            X0V[r_] = MG0[r_] * fast_rcp(acc0_[r_] + bias0);                 \
            X1V[r_] = MG1[r_] * fast_rcp(acc1_[r_] + bias1);                 \
            (DST)[m_ * XS + t0n] = (short)bf16_rne(X0V[r_]);                 \
            (DST)[m_ * XS + t1n] = (short)bf16_rne(X1V[r_]);                 \
        }                                                                    \
        accP0_ = acc0_; accP1_ = acc1_;                                      \
    }

// ---------------------------------------------------------------------------
// Fully fused Sinkhorn (round-11 structure, best measured: 68.8 us total).
// 200 half-iterations max as 16x16x32 bf16 MFMA GEMMs + fused plan-renorm
// cost epilogue. Warm start b0 = nu (epilogue is exactly scale-invariant over
// the fixed-point family (a,b)->(c a, b/c)). Early exit when the ODD-half
// MFMA accs are bf16-bit-stationary: b_n == b_{n-1} (bit) => a_{n+1} = a_n
// => all future iterates repeat, by induction (R13-verified, absmax 0.0).
// Block = 16 batch rows, 4 waves; wave w owns N-tiles {2w, 2w+1} (N pad 128).
// ---------------------------------------------------------------------------
extern "C" __global__ void __launch_bounds__(256)
sk_fused(const float* __restrict__ pred, const int* __restrict__ target,
         float* __restrict__ out, int rows)
{
    __shared__ short xs[2 * XBUF];
    __shared__ __align__(16) float aux[RPB * 104];  // muL pre-loop; SsumP/zP/sclS post
    __shared__ int flagS[4];                        // per-wave change flags (1/pair)

    const int tid  = threadIdx.x;
    const int lane = tid & 63;
    const int wave = tid >> 6;        // 0..3
    const int quad = lane >> 4;       // 0..3
    const int lc   = lane & 15;
    const int row0 = blockIdx.x * RPB;

    // ---- mu = normalize(softmax(pred_row) + STAB): 16 threads per row ----
    {
        const int r = tid >> 4;       // 0..15
        const int c = tid & 15;
        const float* p = pred + (size_t)(row0 + r) * NCLS;
        const float l2e = 1.44269504089f;
        float v[7];
        float mx = -3.4e38f;
#pragma unroll
        for (int q = 0; q < 7; ++q) {
            int j = c + q * 16;
            v[q] = (j < NCLS) ? p[j] : -3.4e38f;
            mx = fmaxf(mx, v[q]);
        }
#pragma unroll
        for (int m = 8; m >= 1; m >>= 1) mx = fmaxf(mx, __shfl_xor(mx, m, 64));
        float s = 0.f;
#pragma unroll
        for (int q = 0; q < 7; ++q) {
            v[q] = (c + q * 16 < NCLS) ? fast_exp2((v[q] - mx) * l2e) : 0.f;
            s += v[q];
        }
#pragma unroll
        for (int m = 8; m >= 1; m >>= 1) s += __shfl_xor(s, m, 64);
        float invS = 1.f / s;
        float s2 = 0.f;
#pragma unroll
        for (int q = 0; q < 7; ++q) {
            if (c + q * 16 < NCLS) { v[q] = v[q] * invS + 1e-6f; s2 += v[q]; }
        }
#pragma unroll
        for (int m = 8; m >= 1; m >>= 1) s2 += __shfl_xor(s2, m, 64);
        float invM = 1.f / s2;
#pragma unroll
        for (int q = 0; q < 7; ++q) {
            int j = c + q * 16;
            if (j < NCLS) aux[r * 104 + j] = v[q] * invM;
        }
    }

    // ---- this wave's N-columns ----
    const int t0n = (2 * wave) * 16 + lc;
    const int t1n = (2 * wave + 1) * 16 + lc;
    const float bias0 = (t0n >= NCLS) ? 1.0f : 0.0f;   // keep rcp input > 0 on pad cols
    const float bias1 = (t1n >= NCLS) ? 1.0f : 0.0f;

    // ---- static B-fragments: B[k=quad*8+j][n] = w(k-n), bf16, Toeplitz ----
    const float c2 = -14.4269504089f / 9801.0f;        // -10*log2(e)/9801
    bf16x8 B0[4], B1[4];
#pragma unroll
    for (int s = 0; s < 4; ++s) {
#pragma unroll
        for (int j = 0; j < 8; ++j) {
            int k  = s * 32 + quad * 8 + j;
            int d0 = k - t0n;
            int d1 = k - t1n;
            B0[s][j] = (short)bf16_rne(fast_exp2(c2 * (float)(d0 * d0)));
            B1[s][j] = (short)bf16_rne(fast_exp2(c2 * (float)(d1 * d1)));
        }
    }

    __syncthreads();   // muL ready

    // ---- marginal fragments in C-layout (row m = quad*4+r, col n) ----
    f32x4 mu0f, mu1f, nu0f, nu1f;
    const float invN = 1.0f / (1.0f + (float)NCLS * 1e-6f);
#pragma unroll
    for (int r = 0; r < 4; ++r) {
        int m = quad * 4 + r;
        mu0f[r] = (t0n < NCLS) ? aux[m * 104 + t0n] : 0.f;
        mu1f[r] = (t1n < NCLS) ? aux[m * 104 + t1n] : 0.f;
        int tg = (int)target[row0 + m];
        nu0f[r] = (t0n < NCLS) ? ((((t0n == tg) ? 1.f : 0.f) + 1e-6f) * invN) : 0.f;
        nu1f[r] = (t1n < NCLS) ? ((((t1n == tg) ? 1.f : 0.f) + 1e-6f) * invN) : 0.f;
    }

    // ---- WARM START: x = b0 = nu (pad cols 0); buffer 0 ----
#pragma unroll
    for (int r = 0; r < 4; ++r) {
        int m = quad * 4 + r;
        xs[m * XS + t0n] = (short)bf16_rne(nu0f[r]);
        xs[m * XS + t1n] = (short)bf16_rne(nu1f[r]);
    }
    __syncthreads();

    // ---- main pair loop with odd-half stationarity early-exit (<= 99 pairs) ----
    f32x4 pvO0 = {-1.f,-1.f,-1.f,-1.f}, pvO1 = pvO0;
    f32x4 xT0, xT1, accP0_, accP1_;
    for (int pair = 0; pair < ITERS - 1; ++pair) {
        // even half: a = mu/(K b), buf0 -> buf1
        HALF(xs, xs + XBUF, mu0f, mu1f, xT0, xT1);
        __syncthreads();
        // odd half: b = nu/(K a), buf1 -> buf0
        HALF(xs + XBUF, xs, nu0f, nu1f, xT0, xT1);
        bool chgO = any_ne(accP0_, pvO0) || any_ne(accP1_, pvO1);
        pvO0 = accP0_; pvO1 = accP1_;
        int anyv = __any((int)chgO);
        if (lane == 0) flagS[wave] = anyv;
        __syncthreads();
        if ((flagS[0] | flagS[1] | flagS[2] | flagS[3]) == 0) break;
    }

    // ---- capture pair: final a (fp32) and b (fp32); b bf16 lands in buf0 ----
    f32x4 aR0, aR1, bR0, bR1;
    HALF(xs, xs + XBUF, mu0f, mu1f, aR0, aR1);
    __syncthreads();
    HALF(xs + XBUF, xs, nu0f, nu1f, bR0, bR1);
    __syncthreads();

    // ================= fused epilogue (round-10-verified math) =================
    // t = K b  (A from buffer 0)
    f32x4 t0a = {0.f, 0.f, 0.f, 0.f};
    f32x4 t1a = {0.f, 0.f, 0.f, 0.f};
    {
        bf16x8 A[4];
#pragma unroll
        for (int s = 0; s < 4; ++s)
            A[s] = *(const bf16x8*)(xs + lc * XS + s * 32 + quad * 8);
#pragma unroll
        for (int s = 0; s < 4; ++s) {
            t0a = MFMA_B(A[s], B0[s], t0a);
            t1a = MFMA_B(A[s], B1[s], t1a);
        }
    }

    // scl = mu / (a*t + n*STAB);  a' = a*scl.  Write a' (buf1) and scl bf16.
    float* SsumP = aux;                     // [4 waves][16 m] floats (256 B)
    float* zP    = aux + 64;                // [4] block-reduce slots
    short* sclS  = (short*)(aux + 128);     // [RPB][XS] bf16 (4352 B)
    short* apS   = xs + XBUF;               // buffer 1, a dead

#pragma unroll
    for (int r = 0; r < 4; ++r) {
        int m = quad * 4 + r;
        float scl0 = mu0f[r] * fast_rcp(fmaf(aR0[r], t0a[r], (float)NCLS * 1e-6f));
        float scl1 = mu1f[r] * fast_rcp(fmaf(aR1[r], t1a[r], (float)NCLS * 1e-6f));
        apS[m * XS + t0n]  = (short)bf16_rne(aR0[r] * scl0);
        apS[m * XS + t1n]  = (short)bf16_rne(aR1[r] * scl1);
        sclS[m * XS + t0n] = (short)bf16_rne(scl0);
        sclS[m * XS + t1n] = (short)bf16_rne(scl1);
        // partial Ssum over this wave's 32 cols (16-lane quad reduce)
        float ps = scl0 + scl1;
#pragma unroll
        for (int w = 8; w >= 1; w >>= 1) ps += __shfl_xor(ps, w, 64);
        if (lc == 0) SsumP[wave * 16 + m] = ps;
    }
    __syncthreads();

    // Ssum[m] = sum over 4 waves
    f32x4 Ssum;
#pragma unroll
    for (int r = 0; r < 4; ++r) {
        int m = quad * 4 + r;
        Ssum[r] = SsumP[m] + SsumP[16 + m] + SsumP[32 + m] + SsumP[48 + m];
    }

    // B-frags for K.C and C (Toeplitz): KC(d) = K(d)*d^2/9801, C(d) = d^2/9801
    bf16x8 KC0[4], KC1[4], C0[4], C1[4];
    const float cinv = 1.0f / 9801.0f;
#pragma unroll
    for (int s = 0; s < 4; ++s) {
#pragma unroll
        for (int j = 0; j < 8; ++j) {
            int k  = s * 32 + quad * 8 + j;
            int d0 = k - t0n;
            int d1 = k - t1n;
            float c0 = (float)(d0 * d0) * cinv;
            float c1 = (float)(d1 * d1) * cinv;
            KC0[s][j] = (short)bf16_rne(fast_exp2(c2 * (float)(d0 * d0)) * c0);
            KC1[s][j] = (short)bf16_rne(fast_exp2(c2 * (float)(d1 * d1)) * c1);
            C0[s][j]  = (short)bf16_rne(c0);
            C1[s][j]  = (short)bf16_rne(c1);
        }
    }

    // q = K a',  mm = (K.C) a',  cs = C scl   (A-frags from apS / sclS)
    f32x4 q0 = {0,0,0,0}, q1 = {0,0,0,0};
    f32x4 m0 = {0,0,0,0}, m1 = {0,0,0,0};
    f32x4 s0 = {0,0,0,0}, s1 = {0,0,0,0};
    {
        bf16x8 Aa[4], As[4];
#pragma unroll
        for (int s = 0; s < 4; ++s) {
            Aa[s] = *(const bf16x8*)(apS  + lc * XS + s * 32 + quad * 8);
            As[s] = *(const bf16x8*)(sclS + lc * XS + s * 32 + quad * 8);
        }
#pragma unroll
        for (int s = 0; s < 4; ++s) {
            q0 = MFMA_B(Aa[s], B0[s],  q0);
            q1 = MFMA_B(Aa[s], B1[s],  q1);
            m0 = MFMA_B(Aa[s], KC0[s], m0);
            m1 = MFMA_B(Aa[s], KC1[s], m1);
            s0 = MFMA_B(As[s], C0[s],  s0);
            s1 = MFMA_B(As[s], C1[s],  s1);
        }
    }

    // cost: z = sum_j nu_j/(b_j q_j + STAB*Ssum) * (b_j mm_j + STAB*cs_j)
    float z = 0.f;
#pragma unroll
    for (int r = 0; r < 4; ++r) {
        float col0 = fmaf(bR0[r], q0[r], 1e-6f * Ssum[r]);
        float col1 = fmaf(bR1[r], q1[r], 1e-6f * Ssum[r]);
        float in0  = fmaf(bR0[r], m0[r], 1e-6f * s0[r]);
        float in1  = fmaf(bR1[r], m1[r], 1e-6f * s1[r]);
        z += nu0f[r] * fast_rcp(col0) * in0 + nu1f[r] * fast_rcp(col1) * in1;
    }
    z = wave_sum(z);
    if (lane == 0) zP[wave] = z;
    __syncthreads();
    if (tid == 0) {
        float tot = zP[0] + zP[1] + zP[2] + zP[3];
        atomicAdd(out, tot / (float)rows);
    }
}

extern "C" void kernel_launch(void* const* d_in, const int* in_sizes, int n_in,
                              void* d_out, int out_size, void* d_ws, size_t ws_size,
                              hipStream_t stream)
{
    const float* pred   = (const float*)d_in[0];
    const int*   target = (const int*)d_in[1];
    float*       out    = (float*)d_out;
    const int    rows   = in_sizes[0] / NCLS;   // 4096

    hipLaunchKernelGGL(sk_zero_out, dim3(1), dim3(1), 0, stream, out);
    hipLaunchKernelGGL(sk_fused, dim3(rows / RPB), dim3(256), 0, stream,
                       pred, target, out, rows);
}